// Round 3
// baseline (116.420 us; speedup 1.0000x reference)
//
#include <hip/hip_runtime.h>

// Problem: shape (32, 2, 640, 640) fp32 pred/target.
// out = sum_central(d^2)/3276800 + sum_periph(|d|)/9830400, d = pred - target,
// central = columns [240,400) of last dim, sums over batch+both channels.
//
// R2 -> R3: fuse the finalize into the main kernel (last-block-done pattern)
// to kill the ~4us second dispatch. Coherence per G16: release fence +
// agent-scope atomic counter; last block reads partials with agent-scope
// atomic loads (bypasses stale per-XCD L2 lines from the previous replay).
// Counter zeroed each call via 4-byte hipMemsetAsync (graph-capturable).
//
// Geometry (unchanged from R2): N4 = 6,553,600 float4 per tensor.
//   1280 blocks x 256 = 327,680 threads; ITERS = 20 (compile-time).
//   stride 327,680 = 160*2048 -> (tid + k*stride) % 160 == tid % 160,
//   so the central/periphery predicate is constant per thread.

#define NBLOCKS 1280
#define NTHREADS 256
#define NTOTAL (NBLOCKS * NTHREADS)   // 327680
#define ITERS 20

__global__ __launch_bounds__(NTHREADS) void
fused_kernel(const float4* __restrict__ p4,
             const float4* __restrict__ t4,
             unsigned int* __restrict__ counter,
             float2* __restrict__ partials,
             float* __restrict__ out) {
    int tid = blockIdx.x * NTHREADS + threadIdx.x;

    // Row is 160 float4s; central float4 columns are [60, 100).
    int w4 = tid % 160;
    bool central = (w4 >= 60) && (w4 < 100);

    float acc_sq = 0.0f;
    float acc_abs = 0.0f;

    #pragma unroll 4
    for (int k = 0; k < ITERS; ++k) {
        int i = tid + k * NTOTAL;
        float4 p = p4[i];
        float4 t = t4[i];
        float d0 = p.x - t.x;
        float d1 = p.y - t.y;
        float d2 = p.z - t.z;
        float d3 = p.w - t.w;
        float s = d0 * d0 + d1 * d1 + d2 * d2 + d3 * d3;
        float a = fabsf(d0) + fabsf(d1) + fabsf(d2) + fabsf(d3);
        acc_sq  += central ? s : 0.0f;
        acc_abs += central ? 0.0f : a;
    }

    // Wave (64-lane) shuffle reduction.
    for (int off = 32; off > 0; off >>= 1) {
        acc_sq  += __shfl_down(acc_sq,  off, 64);
        acc_abs += __shfl_down(acc_abs, off, 64);
    }

    __shared__ float s_sq[NTHREADS / 64];
    __shared__ float s_abs[NTHREADS / 64];
    __shared__ int amLast;
    int lane = threadIdx.x & 63;
    int wave = threadIdx.x >> 6;
    if (lane == 0) {
        s_sq[wave] = acc_sq;
        s_abs[wave] = acc_abs;
    }
    __syncthreads();

    if (threadIdx.x == 0) {
        float sq = s_sq[0] + s_sq[1] + s_sq[2] + s_sq[3];
        float ab = s_abs[0] + s_abs[1] + s_abs[2] + s_abs[3];
        // Agent-scope stores so the flush below makes them globally visible.
        __hip_atomic_store(&partials[blockIdx.x].x, sq,
                           __ATOMIC_RELAXED, __HIP_MEMORY_SCOPE_AGENT);
        __hip_atomic_store(&partials[blockIdx.x].y, ab,
                           __ATOMIC_RELAXED, __HIP_MEMORY_SCOPE_AGENT);
        __threadfence();  // release: partial visible before counter bump
        unsigned int prev = __hip_atomic_fetch_add(counter, 1u,
                                                   __ATOMIC_ACQ_REL,
                                                   __HIP_MEMORY_SCOPE_AGENT);
        amLast = (prev == NBLOCKS - 1) ? 1 : 0;
    }
    __syncthreads();

    if (amLast) {
        // Exactly one block runs this, after all partials are globally visible.
        double dsq = 0.0, dab = 0.0;
        for (int i = threadIdx.x; i < NBLOCKS; i += NTHREADS) {
            // Agent-scope loads: bypass any stale local L1/L2 copy.
            float x = __hip_atomic_load(&partials[i].x,
                                        __ATOMIC_RELAXED, __HIP_MEMORY_SCOPE_AGENT);
            float y = __hip_atomic_load(&partials[i].y,
                                        __ATOMIC_RELAXED, __HIP_MEMORY_SCOPE_AGENT);
            dsq += (double)x;
            dab += (double)y;
        }
        for (int off = 32; off > 0; off >>= 1) {
            dsq += __shfl_down(dsq, off, 64);
            dab += __shfl_down(dab, off, 64);
        }
        __shared__ double d_sq[NTHREADS / 64];
        __shared__ double d_ab[NTHREADS / 64];
        if (lane == 0) {
            d_sq[wave] = dsq;
            d_ab[wave] = dab;
        }
        __syncthreads();
        if (threadIdx.x == 0) {
            double fsq = d_sq[0] + d_sq[1] + d_sq[2] + d_sq[3];
            double fab = d_ab[0] + d_ab[1] + d_ab[2] + d_ab[3];
            // central denom = 32*640*160, periphery denom = 32*640*480
            out[0] = (float)(fsq / 3276800.0 + fab / 9830400.0);
        }
    }
}

extern "C" void kernel_launch(void* const* d_in, const int* in_sizes, int n_in,
                              void* d_out, int out_size, void* d_ws, size_t ws_size,
                              hipStream_t stream) {
    const float4* pred = (const float4*)d_in[0];
    const float4* targ = (const float4*)d_in[1];
    float* out = (float*)d_out;

    unsigned int* counter = (unsigned int*)d_ws;                 // 4 B @ offset 0
    float2* partials = (float2*)((char*)d_ws + 256);             // 1280 float2

    hipMemsetAsync(d_ws, 0, 4, stream);  // reset arrival counter (graph-safe)
    fused_kernel<<<NBLOCKS, NTHREADS, 0, stream>>>(pred, targ, counter,
                                                   partials, out);
}

// Round 4
// 38.455 us; speedup vs baseline: 3.0275x; 3.0275x over previous
//
#include <hip/hip_runtime.h>

// Problem: shape (32, 2, 640, 640) fp32 pred/target.
// out = sum_central(d^2)/3276800 + sum_periph(|d|)/9830400, d = pred - target,
// central = columns [240,400) of last dim, sums over batch+both channels.
//
// R3 post-mortem: last-block-done fusion REGRESSED 42->116us. Per-block
// agent-scope release fences (needed across non-coherent XCD L2s) caused an
// L2 writeback storm that throttled the streaming reads (HBM BW 1380->542
// GB/s, same FETCH_SIZE). Two dispatches are cheaper than device-scope
// fences on gfx950. Reverted to the R2 two-kernel structure.
//
// R4 deltas vs R2: (1) unroll 10 (more float4 loads in flight per thread,
// staying under the 64-VGPR occupancy cliff); (2) final kernel widened to
// 256 threads with float4 loads (2.5 independent rounds instead of 20).
//
// Geometry: N4 = 6,553,600 float4 per tensor.
//   1280 blocks x 256 = 327,680 threads = 5 blocks/CU; ITERS = 20.
//   stride 327,680 = 160*2048 -> (tid + k*stride) % 160 == tid % 160,
//   so the central/periphery predicate is constant per thread.

#define NBLOCKS 1280
#define NTHREADS 256
#define NTOTAL (NBLOCKS * NTHREADS)   // 327680
#define ITERS 20

__global__ __launch_bounds__(NTHREADS) void
partial_kernel(const float4* __restrict__ p4,
               const float4* __restrict__ t4,
               float2* __restrict__ partials) {
    int tid = blockIdx.x * NTHREADS + threadIdx.x;

    // Row is 160 float4s; central float4 columns are [60, 100).
    int w4 = tid % 160;
    bool central = (w4 >= 60) && (w4 < 100);

    float acc_sq = 0.0f;
    float acc_abs = 0.0f;

    #pragma unroll 10
    for (int k = 0; k < ITERS; ++k) {
        int i = tid + k * NTOTAL;
        float4 p = p4[i];
        float4 t = t4[i];
        float d0 = p.x - t.x;
        float d1 = p.y - t.y;
        float d2 = p.z - t.z;
        float d3 = p.w - t.w;
        float s = d0 * d0 + d1 * d1 + d2 * d2 + d3 * d3;
        float a = fabsf(d0) + fabsf(d1) + fabsf(d2) + fabsf(d3);
        acc_sq  += central ? s : 0.0f;
        acc_abs += central ? 0.0f : a;
    }

    // Wave (64-lane) shuffle reduction.
    for (int off = 32; off > 0; off >>= 1) {
        acc_sq  += __shfl_down(acc_sq,  off, 64);
        acc_abs += __shfl_down(acc_abs, off, 64);
    }

    __shared__ float s_sq[NTHREADS / 64];
    __shared__ float s_abs[NTHREADS / 64];
    int lane = threadIdx.x & 63;
    int wave = threadIdx.x >> 6;
    if (lane == 0) {
        s_sq[wave] = acc_sq;
        s_abs[wave] = acc_abs;
    }
    __syncthreads();
    if (threadIdx.x == 0) {
        partials[blockIdx.x] =
            make_float2(s_sq[0] + s_sq[1] + s_sq[2] + s_sq[3],
                        s_abs[0] + s_abs[1] + s_abs[2] + s_abs[3]);
    }
}

__global__ __launch_bounds__(256) void
final_kernel(const float4* __restrict__ part4,   // 1280 float2 = 640 float4
             float* __restrict__ out) {
    double dsq = 0.0, dab = 0.0;
    // 640 float4 over 256 threads: 2.5 rounds, all loads independent.
    for (int i = threadIdx.x; i < NBLOCKS / 2; i += 256) {
        float4 v = part4[i];          // {sq0, ab0, sq1, ab1}
        dsq += (double)v.x + (double)v.z;
        dab += (double)v.y + (double)v.w;
    }
    for (int off = 32; off > 0; off >>= 1) {
        dsq += __shfl_down(dsq, off, 64);
        dab += __shfl_down(dab, off, 64);
    }
    __shared__ double d_sq[4];
    __shared__ double d_ab[4];
    int lane = threadIdx.x & 63;
    int wave = threadIdx.x >> 6;
    if (lane == 0) {
        d_sq[wave] = dsq;
        d_ab[wave] = dab;
    }
    __syncthreads();
    if (threadIdx.x == 0) {
        double fsq = d_sq[0] + d_sq[1] + d_sq[2] + d_sq[3];
        double fab = d_ab[0] + d_ab[1] + d_ab[2] + d_ab[3];
        // central denom = 32*640*160, periphery denom = 32*640*480
        out[0] = (float)(fsq / 3276800.0 + fab / 9830400.0);
    }
}

extern "C" void kernel_launch(void* const* d_in, const int* in_sizes, int n_in,
                              void* d_out, int out_size, void* d_ws, size_t ws_size,
                              hipStream_t stream) {
    const float4* pred = (const float4*)d_in[0];
    const float4* targ = (const float4*)d_in[1];
    float* out = (float*)d_out;
    float2* partials = (float2*)d_ws;

    partial_kernel<<<NBLOCKS, NTHREADS, 0, stream>>>(pred, targ, partials);
    final_kernel<<<1, 256, 0, stream>>>((const float4*)partials, out);
}

// Round 5
// 38.279 us; speedup vs baseline: 3.0414x; 1.0046x over previous
//
#include <hip/hip_runtime.h>

// Problem: shape (32, 2, 640, 640) fp32 pred/target.
// out = sum_central(d^2)/3276800 + sum_periph(|d|)/9830400, d = pred - target,
// central = columns [240,400) of last dim, sums over batch+both channels.
//
// R4: 38.45us total = partial ~34.5us (6.1 TB/s delivered, 97% of float4-copy
// ceiling, half L3-served) + ~3.5-4us finalize dispatch. R3 proved fusing the
// finalize via last-block-done costs 3x more (per-block device-scope fences
// = L2 writeback storm) than the second dispatch.
//
// R5 probe (single variable): occupancy 38% -> 100%. Grid 1280 -> 2560
// blocks, ITERS 20 -> 10. Tests whether the partial kernel is limited by
// outstanding-request concurrency (more waves -> faster) or by delivered
// bandwidth (~6.1 TB/s, unchanged). If unchanged: roofline.
//
// Geometry: N4 = 6,553,600 float4 per tensor.
//   2560 blocks x 256 = 655,360 threads; ITERS = 10 (compile-time).
//   655,360 = 160*4096 -> (tid + k*stride) % 160 == tid % 160,
//   so the central/periphery predicate is constant per thread.

#define NBLOCKS 2560
#define NTHREADS 256
#define NTOTAL (NBLOCKS * NTHREADS)   // 655360
#define ITERS 10

__global__ __launch_bounds__(NTHREADS) void
partial_kernel(const float4* __restrict__ p4,
               const float4* __restrict__ t4,
               float2* __restrict__ partials) {
    int tid = blockIdx.x * NTHREADS + threadIdx.x;

    // Row is 160 float4s; central float4 columns are [60, 100).
    int w4 = tid % 160;
    bool central = (w4 >= 60) && (w4 < 100);

    float acc_sq = 0.0f;
    float acc_abs = 0.0f;

    #pragma unroll 10
    for (int k = 0; k < ITERS; ++k) {
        int i = tid + k * NTOTAL;
        float4 p = p4[i];
        float4 t = t4[i];
        float d0 = p.x - t.x;
        float d1 = p.y - t.y;
        float d2 = p.z - t.z;
        float d3 = p.w - t.w;
        float s = d0 * d0 + d1 * d1 + d2 * d2 + d3 * d3;
        float a = fabsf(d0) + fabsf(d1) + fabsf(d2) + fabsf(d3);
        acc_sq  += central ? s : 0.0f;
        acc_abs += central ? 0.0f : a;
    }

    // Wave (64-lane) shuffle reduction.
    for (int off = 32; off > 0; off >>= 1) {
        acc_sq  += __shfl_down(acc_sq,  off, 64);
        acc_abs += __shfl_down(acc_abs, off, 64);
    }

    __shared__ float s_sq[NTHREADS / 64];
    __shared__ float s_abs[NTHREADS / 64];
    int lane = threadIdx.x & 63;
    int wave = threadIdx.x >> 6;
    if (lane == 0) {
        s_sq[wave] = acc_sq;
        s_abs[wave] = acc_abs;
    }
    __syncthreads();
    if (threadIdx.x == 0) {
        partials[blockIdx.x] =
            make_float2(s_sq[0] + s_sq[1] + s_sq[2] + s_sq[3],
                        s_abs[0] + s_abs[1] + s_abs[2] + s_abs[3]);
    }
}

__global__ __launch_bounds__(256) void
final_kernel(const float4* __restrict__ part4,   // 2560 float2 = 1280 float4
             float* __restrict__ out) {
    double dsq = 0.0, dab = 0.0;
    // 1280 float4 over 256 threads: 5 rounds, all loads independent.
    for (int i = threadIdx.x; i < NBLOCKS / 2; i += 256) {
        float4 v = part4[i];          // {sq0, ab0, sq1, ab1}
        dsq += (double)v.x + (double)v.z;
        dab += (double)v.y + (double)v.w;
    }
    for (int off = 32; off > 0; off >>= 1) {
        dsq += __shfl_down(dsq, off, 64);
        dab += __shfl_down(dab, off, 64);
    }
    __shared__ double d_sq[4];
    __shared__ double d_ab[4];
    int lane = threadIdx.x & 63;
    int wave = threadIdx.x >> 6;
    if (lane == 0) {
        d_sq[wave] = dsq;
        d_ab[wave] = dab;
    }
    __syncthreads();
    if (threadIdx.x == 0) {
        double fsq = d_sq[0] + d_sq[1] + d_sq[2] + d_sq[3];
        double fab = d_ab[0] + d_ab[1] + d_ab[2] + d_ab[3];
        // central denom = 32*640*160, periphery denom = 32*640*480
        out[0] = (float)(fsq / 3276800.0 + fab / 9830400.0);
    }
}

extern "C" void kernel_launch(void* const* d_in, const int* in_sizes, int n_in,
                              void* d_out, int out_size, void* d_ws, size_t ws_size,
                              hipStream_t stream) {
    const float4* pred = (const float4*)d_in[0];
    const float4* targ = (const float4*)d_in[1];
    float* out = (float*)d_out;
    float2* partials = (float2*)d_ws;

    partial_kernel<<<NBLOCKS, NTHREADS, 0, stream>>>(pred, targ, partials);
    final_kernel<<<1, 256, 0, stream>>>((const float4*)partials, out);
}